// Round 4
// baseline (191.033 us; speedup 1.0000x reference)
//
#include <hip/hip_runtime.h>

// DequantSiluAndMulQuant: x int32 [8192, 22016], scale f32 scalar.
// d = 11008. tmp = silu(x[:, :d]*s) * (x[:, d:]*s)
// row_scale = max|tmp| / 127 ; q = clip(rint(tmp/row_scale), -128, 127)
// d_out (float32): q flat [8192*11008] followed by row_scale [8192].
//
// R3: 2 rows/block, pipelined so row1 loads are issued while row0 stores
// drain (kills the read-pipe bubble of the 2-phase structure).

constexpr int NUM_TOKENS = 8192;
constexpr int TWO_D      = 22016;
constexpr int D          = TWO_D / 2;        // 11008
constexpr int VEC        = D / 4;            // 2752 float4 per half-row
constexpr int THREADS    = 512;
constexpr int NWAVES     = THREADS / 64;     // 8
constexpr int ITERS      = (VEC + THREADS - 1) / THREADS;  // 6
constexpr int FULL_ITERS = VEC / THREADS;    // 5
constexpr int REM        = VEC % THREADS;    // 192

typedef int   i32x4 __attribute__((ext_vector_type(4)));
typedef float f32x4 __attribute__((ext_vector_type(4)));

__device__ __forceinline__ float silu_mul(float g, float u) {
    // silu(g)*u = g * rcp(1 + exp(-g)) * u   (v_rcp_f32: 1 ulp, fine for int8 quant)
    return g * __builtin_amdgcn_rcpf(1.0f + __expf(-g)) * u;
}

__device__ __forceinline__ f32x4 silu4(const i32x4 gv, const i32x4 uv, float ds, float& m) {
    f32x4 r;
    r.x = silu_mul((float)gv.x * ds, (float)uv.x * ds);
    r.y = silu_mul((float)gv.y * ds, (float)uv.y * ds);
    r.z = silu_mul((float)gv.z * ds, (float)uv.z * ds);
    r.w = silu_mul((float)gv.w * ds, (float)uv.w * ds);
    m = fmaxf(m, fmaxf(fmaxf(fabsf(r.x), fabsf(r.y)),
                       fmaxf(fabsf(r.z), fabsf(r.w))));
    return r;
}

__device__ __forceinline__ f32x4 quant4(const f32x4 r, float inv) {
    f32x4 q;
    q.x = fminf(fmaxf(rintf(r.x * inv), -128.0f), 127.0f);
    q.y = fminf(fmaxf(rintf(r.y * inv), -128.0f), 127.0f);
    q.z = fminf(fmaxf(rintf(r.z * inv), -128.0f), 127.0f);
    q.w = fminf(fmaxf(rintf(r.w * inv), -128.0f), 127.0f);
    return q;
}

__device__ __forceinline__ float block_max(float m, volatile float* smax, int t) {
#pragma unroll
    for (int off = 32; off >= 1; off >>= 1)
        m = fmaxf(m, __shfl_xor(m, off, 64));
    if ((t & 63) == 0) smax[t >> 6] = m;
    __syncthreads();
    float r = smax[0];
#pragma unroll
    for (int w = 1; w < NWAVES; ++w) r = fmaxf(r, smax[w]);
    return r;
}

__global__ __launch_bounds__(THREADS)
void dsmq_kernel(const i32x4* __restrict__ x,
                 const float* __restrict__ dsp,
                 f32x4* __restrict__ qout,
                 float* __restrict__ sout)
{
    const int row0 = blockIdx.x * 2;
    const int row1 = row0 + 1;
    const int t    = threadIdx.x;
    const float ds = *dsp;

    const i32x4* g0 = x + (size_t)row0 * (TWO_D / 4);
    const i32x4* u0 = g0 + VEC;
    const i32x4* g1 = x + (size_t)row1 * (TWO_D / 4);
    const i32x4* u1 = g1 + VEC;
    f32x4* q0 = qout + (size_t)row0 * VEC;
    f32x4* q1 = qout + (size_t)row1 * VEC;

    __shared__ float smax0[NWAVES];
    __shared__ float smax1[NWAVES];

    f32x4 tmp[ITERS];
    float m0 = 0.0f;

    // ---- phase A: load + compute row0 ----
#pragma unroll
    for (int k = 0; k < ITERS; ++k) {
        const int idx = k * THREADS + t;
        if (k < FULL_ITERS || t < REM) {
            const i32x4 gv = __builtin_nontemporal_load(&g0[idx]);
            const i32x4 uv = __builtin_nontemporal_load(&u0[idx]);
            tmp[k] = silu4(gv, uv, ds, m0);
        }
    }
    m0 = block_max(m0, smax0, t);
    const float inv0 = (m0 > 0.0f) ? 127.0f / m0 : 0.0f;
    if (t == 0) sout[row0] = m0 / 127.0f;

    // ---- phase B: issue row1 loads || store row0 || compute row1 ----
    float m1 = 0.0f;
#pragma unroll
    for (int k = 0; k < ITERS; ++k) {
        const int idx = k * THREADS + t;
        if (k < FULL_ITERS || t < REM) {
            const i32x4 gv = __builtin_nontemporal_load(&g1[idx]);
            const i32x4 uv = __builtin_nontemporal_load(&u1[idx]);
            __builtin_nontemporal_store(quant4(tmp[k], inv0), &q0[idx]);
            tmp[k] = silu4(gv, uv, ds, m1);
        }
    }
    m1 = block_max(m1, smax1, t);
    const float inv1 = (m1 > 0.0f) ? 127.0f / m1 : 0.0f;
    if (t == 0) sout[row1] = m1 / 127.0f;

    // ---- phase C: store row1 ----
#pragma unroll
    for (int k = 0; k < ITERS; ++k) {
        const int idx = k * THREADS + t;
        if (k < FULL_ITERS || t < REM) {
            __builtin_nontemporal_store(quant4(tmp[k], inv1), &q1[idx]);
        }
    }
}

extern "C" void kernel_launch(void* const* d_in, const int* in_sizes, int n_in,
                              void* d_out, int out_size, void* d_ws, size_t ws_size,
                              hipStream_t stream)
{
    const i32x4* x  = (const i32x4*)d_in[0];
    const float* ds = (const float*)d_in[1];
    f32x4* qout = (f32x4*)d_out;
    float* sout = (float*)d_out + (size_t)NUM_TOKENS * D;
    dsmq_kernel<<<NUM_TOKENS / 2, THREADS, 0, stream>>>(x, ds, qout, sout);
}

// Round 5
// 180.906 us; speedup vs baseline: 1.0560x; 1.0560x over previous
//
#include <hip/hip_runtime.h>

// DequantSiluAndMulQuant: x int32 [8192, 22016], scale f32 scalar.
// d = 11008. tmp = silu(x[:, :d]*s) * (x[:, d:]*s)
// row_scale = max|tmp| / 127 ; q = clip(rint(tmp/row_scale), -128, 127)
// d_out (float32): q flat [8192*11008] followed by row_scale [8192].
//
// Best config (R3): 512 threads, 1 row/block, tmp in registers, nt loads/stores.
// 181 µs = 5.98 TB/s effective = 95% of float4-copy ceiling. R4's 2-row
// pipeline regressed (191 µs) — cross-block TLP already hides phase bubbles.

constexpr int NUM_TOKENS = 8192;
constexpr int TWO_D      = 22016;
constexpr int D          = TWO_D / 2;        // 11008
constexpr int VEC        = D / 4;            // 2752 float4 per half-row
constexpr int THREADS    = 512;
constexpr int NWAVES     = THREADS / 64;     // 8
constexpr int FULL_ITERS = VEC / THREADS;    // 5
constexpr int REM        = VEC % THREADS;    // 192

typedef int   i32x4 __attribute__((ext_vector_type(4)));
typedef float f32x4 __attribute__((ext_vector_type(4)));

__device__ __forceinline__ float silu_mul(float g, float u) {
    // silu(g)*u = g * rcp(1 + exp(-g)) * u   (v_rcp_f32: 1 ulp, fine for int8 quant)
    return g * __builtin_amdgcn_rcpf(1.0f + __expf(-g)) * u;
}

__global__ __launch_bounds__(THREADS)
void dsmq_kernel(const i32x4* __restrict__ x,
                 const float* __restrict__ dsp,
                 f32x4* __restrict__ qout,
                 float* __restrict__ sout)
{
    const int row = blockIdx.x;
    const int t   = threadIdx.x;
    const float ds = *dsp;

    const i32x4* gp = x + (size_t)row * (TWO_D / 4);
    const i32x4* up = gp + VEC;

    f32x4 tmp[FULL_ITERS + 1];
    float m = 0.0f;

#pragma unroll
    for (int k = 0; k <= FULL_ITERS; ++k) {
        const int idx = k * THREADS + t;
        if (k < FULL_ITERS || t < REM) {
            const i32x4 gv = __builtin_nontemporal_load(&gp[idx]);
            const i32x4 uv = __builtin_nontemporal_load(&up[idx]);
            f32x4 r;
            r.x = silu_mul((float)gv.x * ds, (float)uv.x * ds);
            r.y = silu_mul((float)gv.y * ds, (float)uv.y * ds);
            r.z = silu_mul((float)gv.z * ds, (float)uv.z * ds);
            r.w = silu_mul((float)gv.w * ds, (float)uv.w * ds);
            tmp[k] = r;
            m = fmaxf(m, fmaxf(fmaxf(fabsf(r.x), fabsf(r.y)),
                               fmaxf(fabsf(r.z), fabsf(r.w))));
        }
    }

    // wave-level max reduce across 64 lanes
#pragma unroll
    for (int off = 32; off >= 1; off >>= 1)
        m = fmaxf(m, __shfl_xor(m, off, 64));

    __shared__ float smax[NWAVES];
    const int wave = t >> 6;
    if ((t & 63) == 0) smax[wave] = m;
    __syncthreads();
    m = smax[0];
#pragma unroll
    for (int w = 1; w < NWAVES; ++w) m = fmaxf(m, smax[w]);

    const float scale = m / 127.0f;
    const float inv   = (m > 0.0f) ? 127.0f / m : 0.0f;

    if (t == 0) sout[row] = scale;

    f32x4* qp = qout + (size_t)row * VEC;
#pragma unroll
    for (int k = 0; k <= FULL_ITERS; ++k) {
        const int idx = k * THREADS + t;
        if (k < FULL_ITERS || t < REM) {
            const f32x4 r = tmp[k];
            f32x4 q;
            q.x = fminf(fmaxf(rintf(r.x * inv), -128.0f), 127.0f);
            q.y = fminf(fmaxf(rintf(r.y * inv), -128.0f), 127.0f);
            q.z = fminf(fmaxf(rintf(r.z * inv), -128.0f), 127.0f);
            q.w = fminf(fmaxf(rintf(r.w * inv), -128.0f), 127.0f);
            __builtin_nontemporal_store(q, &qp[idx]);
        }
    }
}

extern "C" void kernel_launch(void* const* d_in, const int* in_sizes, int n_in,
                              void* d_out, int out_size, void* d_ws, size_t ws_size,
                              hipStream_t stream)
{
    const i32x4* x  = (const i32x4*)d_in[0];
    const float* ds = (const float*)d_in[1];
    f32x4* qout = (f32x4*)d_out;
    float* sout = (float*)d_out + (size_t)NUM_TOKENS * D;
    dsmq_kernel<<<NUM_TOKENS, THREADS, 0, stream>>>(x, ds, qout, sout);
}